// Round 6
// baseline (249.617 us; speedup 1.0000x reference)
//
#include <hip/hip_runtime.h>

#define INF_F 1e20f
#define B_ 16
#define Q_ 64
#define M_ 512
#define F_ 16
#define D_ 512

typedef __attribute__((ext_vector_type(8))) short short8v;
typedef __attribute__((ext_vector_type(4))) float f32x4;

static __device__ __forceinline__ float bits_f(unsigned u) { return __uint_as_float(u); }

// float4 -> hi bf16x4 (uint2) + residual-lo bf16x4 (uint2), truncation split
static __device__ __forceinline__ void split4(float4 v, uint2& H, uint2& L) {
    unsigned hx = __float_as_uint(v.x) & 0xffff0000u, hy = __float_as_uint(v.y) & 0xffff0000u;
    unsigned hz = __float_as_uint(v.z) & 0xffff0000u, hw = __float_as_uint(v.w) & 0xffff0000u;
    H.x = (hx >> 16) | hy;
    H.y = (hz >> 16) | hw;
    L.x = (__float_as_uint(v.x - bits_f(hx)) >> 16) | (__float_as_uint(v.y - bits_f(hy)) & 0xffff0000u);
    L.y = (__float_as_uint(v.z - bits_f(hz)) >> 16) | (__float_as_uint(v.w - bits_f(hw)) & 0xffff0000u);
}

// K0: build q fragment-image: unit u = [b][kc][lg][row] -> 8 bf16 (hi & lo)
// containing query[b][row][kc*32 + lg*8 .. +7]
__global__ __launch_bounds__(256) void k_q_split(
    const float* __restrict__ q, short8v* __restrict__ qh, short8v* __restrict__ ql)
{
    int u = blockIdx.x * 256 + threadIdx.x;          // 0..65535
    int row = u & 63, lg = (u >> 6) & 3, kc = (u >> 8) & 15, b = u >> 12;
    const float4* q4 = (const float4*)q;
    size_t s = (size_t)(b * 64 + row) * 128 + kc * 8 + lg * 2;
    float4 v0 = q4[s], v1 = q4[s + 1];
    uint2 H0, L0, H1, L1;
    split4(v0, H0, L0);
    split4(v1, H1, L1);
    uint4 H = make_uint4(H0.x, H0.y, H1.x, H1.y);
    uint4 L = make_uint4(L0.x, L0.y, L1.x, L1.y);
    *(uint4*)&qh[u] = H;
    *(uint4*)&ql[u] = L;
}

// K1: fused attention GEMM (bf16 hi/lo 3-term MFMA) + masks + f-max -> att_qm
//     + weighted f-sum of in_memory -> in_mem_base (waves 0-1, L2 re-read)
//     + plain f-sum of out_memory  -> out_mem_sum (waves 2-3, only out read)
// Block: 256 thr = 4 waves; 8 m (128 B-rows) x 64 q; dbuf M-LDS, 1 raw barrier/chunk.
__global__ __launch_bounds__(256) void k_att_mfma(
    const short8v* __restrict__ qh, const short8v* __restrict__ ql,
    const float* __restrict__ in_mem, const float* __restrict__ out_mem,
    const float* __restrict__ ctx_mask, const float* __restrict__ query_mask,
    float* __restrict__ att_qm, float* __restrict__ in_mem_base,
    float* __restrict__ out_mem_sum)
{
    // M-tile: 128 rows x 32 bf16, pitch 40 shorts (80B); granule swz ^((row&1)<<1)
    __shared__ __align__(16) short Mh[2][5120];   // 20 KB
    __shared__ __align__(16) short Ml[2][5120];   // 20 KB

    const int bid = blockIdx.x;
    const int b   = bid & 15;            // XCD pin (b%8): q-image + batch L2 locality
    const int m0  = (bid >> 4) * 8;      // 8 m per block
    const int t   = threadIdx.x;
    const int w   = t >> 6;              // wave 0..3 -> m-tiles {2w, 2w+1}
    const int lane = t & 63;
    const int lr  = lane & 15;           // fragment row (= f for B)
    const int lg  = lane >> 4;           // k-granule 0..3
    const int r0  = t >> 3, c0 = t & 7;  // staging: rows r0+32i, float4-col c0

    // f-sum role: waves 0-1 -> weighted in-sum; waves 2-3 -> out-sum
    const int tt   = t & 127;
    const int msel = tt >> 4, col4 = (tt >> 1) & 7, half = tt & 1;
    const bool is_in = (t < 128);

    float wj[8];
    if (is_in) {
        const float* cm = ctx_mask + ((size_t)b * M_ + m0 + msel) * F_;
        float wv[16]; float mx = -INF_F;
        #pragma unroll
        for (int f = 0; f < 16; ++f) {
            float c = cm[f];
            float v = c - (1.0f - c) * INF_F;
            wv[f] = v; mx = fmaxf(mx, v);
        }
        float sum = 0.f;
        #pragma unroll
        for (int f = 0; f < 16; ++f) { wv[f] = __expf(wv[f] - mx); sum += wv[f]; }
        float inv = 1.0f / sum;
        #pragma unroll
        for (int j = 0; j < 8; ++j) wj[j] = wv[half * 8 + j] * inv;
    } else {
        #pragma unroll
        for (int j = 0; j < 8; ++j) wj[j] = 1.0f;
    }

    const float4* in4 = (const float4*)in_mem;
    const float4* ot4 = (const float4*)out_mem;
    const size_t mb    = (size_t)((b * M_ + m0) * F_) * 128;
    const float4* fsrc = is_in ? in4 : ot4;
    float4* fdst       = is_in ? (float4*)in_mem_base : (float4*)out_mem_sum;
    const size_t fbase = (size_t)((b * M_ + m0 + msel) * F_ + half * 8) * 128 + col4;
    const size_t fob   = (size_t)(b * M_ + m0 + msel) * 128 + col4;
    const int qbase0   = b * 16 * 256 + lg * 64 + lr;   // unit index, + kc*256 + tq*16

    f32x4 acc[2][4];
    #pragma unroll
    for (int i = 0; i < 2; ++i)
        #pragma unroll
        for (int j = 0; j < 4; ++j) acc[i][j] = (f32x4){0, 0, 0, 0};

    float4 stg[4], fv[8];
    short8v qfh[4], qfl[4];

    // prologue: chunk-0 loads
    #pragma unroll
    for (int i = 0; i < 4; ++i) stg[i] = in4[mb + (size_t)(r0 + i * 32) * 128 + c0];
    #pragma unroll
    for (int j = 0; j < 8; ++j) fv[j] = fsrc[fbase + (size_t)j * 128];
    #pragma unroll
    for (int tq = 0; tq < 4; ++tq) { qfh[tq] = qh[qbase0 + tq * 16]; qfl[tq] = ql[qbase0 + tq * 16]; }

#define BODY(kc_, bi_) do {                                                      \
        /* CONV: consume stg -> LDS[bi_] */                                      \
        _Pragma("unroll")                                                        \
        for (int i = 0; i < 4; ++i) {                                            \
            int r = r0 + i * 32;                                                 \
            uint2 H, L; split4(stg[i], H, L);                                    \
            int off = r * 40 + (((c0 >> 1) ^ ((r & 1) << 1)) << 3) + ((c0 & 1) << 2); \
            *(uint2*)&Mh[bi_][off] = H;                                          \
            *(uint2*)&Ml[bi_][off] = L;                                          \
        }                                                                        \
        if ((kc_) < 15) {                                                        \
            _Pragma("unroll")                                                    \
            for (int i = 0; i < 4; ++i)                                          \
                stg[i] = in4[mb + (size_t)(r0 + i * 32) * 128 + ((kc_) + 1) * 8 + c0]; \
        }                                                                        \
        asm volatile("s_waitcnt lgkmcnt(0)" ::: "memory");                       \
        __builtin_amdgcn_s_barrier();                                            \
        /* MFMA: consume qf fragments */                                         \
        _Pragma("unroll")                                                        \
        for (int tm = 0; tm < 2; ++tm) {                                         \
            int row = (2 * w + tm) * 16 + lr;                                    \
            int off = row * 40 + ((lg ^ ((row & 1) << 1)) << 3);                 \
            short8v bh = *(const short8v*)&Mh[bi_][off];                         \
            short8v bl = *(const short8v*)&Ml[bi_][off];                         \
            _Pragma("unroll")                                                    \
            for (int tq = 0; tq < 4; ++tq) {                                     \
                acc[tm][tq] = __builtin_amdgcn_mfma_f32_16x16x32_bf16(qfh[tq], bh, acc[tm][tq], 0, 0, 0); \
                acc[tm][tq] = __builtin_amdgcn_mfma_f32_16x16x32_bf16(qfh[tq], bl, acc[tm][tq], 0, 0, 0); \
                acc[tm][tq] = __builtin_amdgcn_mfma_f32_16x16x32_bf16(qfl[tq], bh, acc[tm][tq], 0, 0, 0); \
            }                                                                    \
        }                                                                        \
        if ((kc_) < 15) {                                                        \
            int qb = qbase0 + ((kc_) + 1) * 256;                                 \
            _Pragma("unroll")                                                    \
            for (int tq = 0; tq < 4; ++tq) { qfh[tq] = qh[qb + tq * 16]; qfl[tq] = ql[qb + tq * 16]; } \
        }                                                                        \
        /* FSUM: consume fv */                                                   \
        {                                                                        \
            float4 s = make_float4(0, 0, 0, 0);                                  \
            _Pragma("unroll")                                                    \
            for (int j = 0; j < 8; ++j) {                                        \
                s.x += wj[j] * fv[j].x; s.y += wj[j] * fv[j].y;                  \
                s.z += wj[j] * fv[j].z; s.w += wj[j] * fv[j].w;                  \
            }                                                                    \
            if ((kc_) < 15) {                                                    \
                _Pragma("unroll")                                                \
                for (int j = 0; j < 8; ++j)                                      \
                    fv[j] = fsrc[fbase + (size_t)j * 128 + ((kc_) + 1) * 8];     \
            }                                                                    \
            s.x += __shfl_xor(s.x, 1, 64); s.y += __shfl_xor(s.y, 1, 64);        \
            s.z += __shfl_xor(s.z, 1, 64); s.w += __shfl_xor(s.w, 1, 64);        \
            if (half == 0) fdst[fob + (kc_) * 8] = s;                            \
        }                                                                        \
    } while (0)

    for (int it = 0; it < 8; ++it) {
        int kc0 = 2 * it, kc1 = 2 * it + 1;
        BODY(kc0, 0);
        BODY(kc1, 1);
    }
#undef BODY

    // masks + max over f (16-lane groups) -> att_qm; wave w owns m-tiles 2w, 2w+1
    #pragma unroll
    for (int tm = 0; tm < 2; ++tm) {
        int m = m0 + 2 * w + tm;
        float cmv = ctx_mask[((size_t)b * M_ + m) * F_ + lr];
        #pragma unroll
        for (int tq = 0; tq < 4; ++tq) {
            #pragma unroll
            for (int rg = 0; rg < 4; ++rg) {
                int q = tq * 16 + lg * 4 + rg;
                float qmv = query_mask[b * Q_ + q];
                float v = acc[tm][tq][rg];
                v = cmv * v - (1.0f - cmv) * INF_F;
                v = qmv * v - (1.0f - qmv) * INF_F;
                #pragma unroll
                for (int sh = 1; sh < 16; sh <<= 1) v = fmaxf(v, __shfl_xor(v, sh, 64));
                if (lr == 0)
                    att_qm[((size_t)b * Q_ + q) * M_ + m] = v;
            }
        }
    }
}

// K2: softmax over M (in-block) + new_query = query + probs @ out_mem_sum
__global__ __launch_bounds__(128) void k_new_query(
    const float* __restrict__ att, const float* __restrict__ query,
    const float* __restrict__ out_sum, float* __restrict__ new_q)
{
    __shared__ float P[8][512];
    int bid = blockIdx.x;
    int b = bid & 15, qc = bid >> 4;
    int t = threadIdx.x;
    {
        int qi = t >> 4, l16 = t & 15;
        const float* row = att + ((size_t)b * Q_ + qc * 8 + qi) * M_;
        float vals[32]; float mx = -INF_F;
        #pragma unroll
        for (int i = 0; i < 32; ++i) { vals[i] = row[l16 + i * 16]; mx = fmaxf(mx, vals[i]); }
        #pragma unroll
        for (int s = 1; s < 16; s <<= 1) mx = fmaxf(mx, __shfl_xor(mx, s, 64));
        float sm = 0.f;
        #pragma unroll
        for (int i = 0; i < 32; ++i) { vals[i] = __expf(vals[i] - mx); sm += vals[i]; }
        #pragma unroll
        for (int s = 1; s < 16; s <<= 1) sm += __shfl_xor(sm, s, 64);
        float inv = 1.0f / sm;
        #pragma unroll
        for (int i = 0; i < 32; ++i) P[qi][l16 + i * 16] = vals[i] * inv;
    }
    __syncthreads();
    int c = t;
    const float4* o4 = (const float4*)out_sum + (size_t)b * M_ * 128 + c;
    const float4* q4 = (const float4*)query + ((size_t)b * Q_ + qc * 8) * 128 + c;
    float4 acc[8];
    #pragma unroll
    for (int qi = 0; qi < 8; ++qi) acc[qi] = q4[(size_t)qi * 128];
    for (int mm = 0; mm < M_; mm += 4) {
        float4 o0 = o4[(size_t)(mm + 0) * 128];
        float4 o1 = o4[(size_t)(mm + 1) * 128];
        float4 o2 = o4[(size_t)(mm + 2) * 128];
        float4 o3 = o4[(size_t)(mm + 3) * 128];
        #pragma unroll
        for (int qi = 0; qi < 8; ++qi) {
            float4 p = *(const float4*)&P[qi][mm];
            acc[qi].x += p.x * o0.x + p.y * o1.x + p.z * o2.x + p.w * o3.x;
            acc[qi].y += p.x * o0.y + p.y * o1.y + p.z * o2.y + p.w * o3.y;
            acc[qi].z += p.x * o0.z + p.y * o1.z + p.z * o2.z + p.w * o3.z;
            acc[qi].w += p.x * o0.w + p.y * o1.w + p.z * o2.w + p.w * o3.w;
        }
    }
    float4* n4 = (float4*)new_q + ((size_t)b * Q_ + qc * 8) * 128 + c;
    #pragma unroll
    for (int qi = 0; qi < 8; ++qi) n4[(size_t)qi * 128] = acc[qi];
}

// K3: softmax over Q (in-block) + in_mem += p2 @ new_query
__global__ __launch_bounds__(128) void k_in_mem(
    const float* __restrict__ att, const float* __restrict__ new_q,
    float* __restrict__ in_mem_io)
{
    __shared__ float P[8][64];
    int bid = blockIdx.x;
    int b = bid & 15, mc = bid >> 4;
    int m0 = mc * 8;
    int t = threadIdx.x;
    {
        int mi = t >> 4, l16 = t & 15;
        float v[4]; float mx = -INF_F;
        #pragma unroll
        for (int i = 0; i < 4; ++i) {
            v[i] = att[((size_t)b * Q_ + l16 + i * 16) * M_ + m0 + mi];
            mx = fmaxf(mx, v[i]);
        }
        #pragma unroll
        for (int s = 1; s < 16; s <<= 1) mx = fmaxf(mx, __shfl_xor(mx, s, 64));
        float sm = 0.f;
        #pragma unroll
        for (int i = 0; i < 4; ++i) { v[i] = __expf(v[i] - mx); sm += v[i]; }
        #pragma unroll
        for (int s = 1; s < 16; s <<= 1) sm += __shfl_xor(sm, s, 64);
        float inv = 1.0f / sm;
        #pragma unroll
        for (int i = 0; i < 4; ++i) P[mi][l16 + i * 16] = v[i] * inv;
    }
    __syncthreads();
    int c = t;
    float4* io = (float4*)in_mem_io + ((size_t)b * M_ + m0) * 128 + c;
    const float4* n4 = (const float4*)new_q + (size_t)b * Q_ * 128 + c;
    float4 acc[8];
    #pragma unroll
    for (int mi = 0; mi < 8; ++mi) acc[mi] = io[(size_t)mi * 128];
    for (int q = 0; q < Q_; q += 4) {
        float4 n0 = n4[(size_t)(q + 0) * 128];
        float4 n1 = n4[(size_t)(q + 1) * 128];
        float4 n2 = n4[(size_t)(q + 2) * 128];
        float4 n3 = n4[(size_t)(q + 3) * 128];
        #pragma unroll
        for (int mi = 0; mi < 8; ++mi) {
            float4 p = *(const float4*)&P[mi][q];
            acc[mi].x += p.x * n0.x + p.y * n1.x + p.z * n2.x + p.w * n3.x;
            acc[mi].y += p.x * n0.y + p.y * n1.y + p.z * n2.y + p.w * n3.y;
            acc[mi].z += p.x * n0.z + p.y * n1.z + p.z * n2.z + p.w * n3.z;
            acc[mi].w += p.x * n0.w + p.y * n1.w + p.z * n2.w + p.w * n3.w;
        }
    }
    #pragma unroll
    for (int mi = 0; mi < 8; ++mi) io[(size_t)mi * 128] = acc[mi];
}

extern "C" void kernel_launch(void* const* d_in, const int* in_sizes, int n_in,
                              void* d_out, int out_size, void* d_ws, size_t ws_size,
                              hipStream_t stream)
{
    const float* query      = (const float*)d_in[0];
    const float* in_mem     = (const float*)d_in[1];
    const float* out_mem    = (const float*)d_in[2];
    const float* ctx_mask   = (const float*)d_in[3];
    const float* query_mask = (const float*)d_in[4];

    float* out = (float*)d_out;
    float* new_q      = out;                             // B*Q*D
    float* in_mem_out = out + (size_t)B_*Q_*D_;          // B*M*D
    float* out_mem_o  = in_mem_out + (size_t)B_*M_*D_;   // B*M*D

    float* ws       = (float*)d_ws;
    float* att_qm   = ws;                                // B*Q*M floats (2 MB)
    short8v* qh     = (short8v*)(ws + (size_t)B_*Q_*M_); // 65536 units (1 MB)
    short8v* ql     = qh + 65536;                        // 1 MB

    hipLaunchKernelGGL(k_q_split, dim3(256), dim3(256), 0, stream, query, qh, ql);
    hipLaunchKernelGGL(k_att_mfma, dim3((M_/8) * B_), dim3(256), 0, stream,
                       qh, ql, in_mem, out_mem, ctx_mask, query_mask,
                       att_qm, in_mem_out, out_mem_o);
    hipLaunchKernelGGL(k_new_query, dim3(8 * B_), dim3(128), 0, stream,
                       att_qm, query, out_mem_o, new_q);
    hipLaunchKernelGGL(k_in_mem, dim3(64 * B_), dim3(128), 0, stream,
                       att_qm, new_q, in_mem_out);
}